// Round 5
// baseline (386.278 us; speedup 1.0000x reference)
//
#include <hip/hip_runtime.h>
#include <cstddef>
#include <cstdint>

static constexpr int Dm   = 1024;
static constexpr int Hh   = 16;
static constexpr int HDd  = 64;
static constexpr int FFd  = 4096;
static constexpr int Ls   = 2048;
static constexpr int Nb   = 2;
static constexpr int Mrows = Nb * Ls;   // 4096

typedef short bf16x8 __attribute__((ext_vector_type(8)));
typedef float f32x4  __attribute__((ext_vector_type(4)));

#if __has_builtin(__builtin_amdgcn_exp2f)
#define EXP2(x) __builtin_amdgcn_exp2f(x)
#else
#define EXP2(x) exp2f(x)
#endif

__device__ __forceinline__ ushort f2b(float f) {        // RNE (pre-pass)
    uint32_t u = __builtin_bit_cast(uint32_t, f);
    u = (u + 0x7FFFu + ((u >> 16) & 1u)) >> 16;
    return (ushort)u;
}
__device__ __forceinline__ ushort f2bf(float f) {       // fast round-half-up
    return (ushort)((__builtin_bit_cast(uint32_t, f) + 0x8000u) >> 16);
}
__device__ __forceinline__ float b2f(ushort b) {
    return __builtin_bit_cast(float, (uint32_t)b << 16);
}

__device__ __forceinline__ void gl2lds16(const ushort* g, ushort* l) {
    __builtin_amdgcn_global_load_lds(
        (const __attribute__((address_space(1))) void*)g,
        (__attribute__((address_space(3))) void*)l, 16, 0, 0);
}

// ---------------------------------------------------------------------------
__global__ __launch_bounds__(256) void convert_bf16(
    const float* __restrict__ src, ushort* __restrict__ dst, int n)
{
    int i = (blockIdx.x * 256 + threadIdx.x) * 4;
    if (i >= n) return;
    float4 v = *(const float4*)(src + i);
    uint2 o;
    o.x = (uint32_t)f2b(v.x) | ((uint32_t)f2b(v.y) << 16);
    o.y = (uint32_t)f2b(v.z) | ((uint32_t)f2b(v.w) << 16);
    *(uint2*)(dst + i) = o;
}

// ---------------------------------------------------------------------------
__global__ __launch_bounds__(256) void transpose_bf16(
    const float* __restrict__ src, ushort* __restrict__ dst, int K, int N)
{
    __shared__ float t[32][33];
    const int k0 = blockIdx.y * 32, n0 = blockIdx.x * 32;
    const int tx = threadIdx.x & 31, ty = threadIdx.x >> 5;
    #pragma unroll
    for (int i = 0; i < 4; ++i)
        t[ty + i * 8][tx] = src[(size_t)(k0 + ty + i * 8) * N + n0 + tx];
    __syncthreads();
    #pragma unroll
    for (int i = 0; i < 4; ++i)
        dst[(size_t)(n0 + ty + i * 8) * K + k0 + tx] = f2b(t[tx][ty + i * 8]);
}

// ---------------------------------------------------------------------------
// bf16 MFMA GEMM, double-buffered LDS, ONE barrier per K-iter.
// C[M,N] = A[M,K] @ Bt[N,K]^T + bias. 128 x TN tile (TN=128|64), 256 thr,
// BK=32, global_load_lds 16B into alternating buffers.
// SPLITK>1: grid.z = K-slice; bf16 partials to Cb + kz*M*N; add3_ln combines.
// T1: XCD-aware tile swizzle so each XCD's L2 keeps a contiguous A-panel run.
// ---------------------------------------------------------------------------
template <int TN, int RELU, int VOUT, int SPLITK>
__global__ __launch_bounds__(256) void gemm_mfma(
    const ushort* __restrict__ A, const ushort* __restrict__ Bt,
    const float* __restrict__ bias,
    ushort* __restrict__ Cb, ushort* __restrict__ vT, int M, int N, int K)
{
    constexpr int NT  = TN / 32;                 // B n-frags per wave
    constexpr int BSZ = TN * 32;                 // Bs shorts per buffer
    __shared__ __align__(16) ushort As[2 * 128 * 32];
    __shared__ __align__(16) ushort Bs[2 * BSZ];

    const int tid  = threadIdx.x;
    int bx, by;
    {
        const int gx = gridDim.x;
        const int nwg = gx * gridDim.y;
        const int lin = blockIdx.y * gx + blockIdx.x;
        const int swz = (lin & 7) * (nwg >> 3) + (lin >> 3);
        by = swz / gx; bx = swz - by * gx;
    }
    const int bm   = by * 128, bn = bx * TN;
    const int wave = tid >> 6, lane = tid & 63;
    const int wm = (wave & 1) * 64;
    const int wn = (wave >> 1) * (TN / 2);
    const int lr = lane & 15, lq = lane >> 4;

    const int KS   = K / SPLITK;                 // K per slice
    const int Koff = (SPLITK > 1) ? blockIdx.z * KS : 0;

    const int rr = wave * 16 + (lane >> 2);
    const int sg = lane & 3;
    const ushort* Ag = A  + (size_t)(bm + rr) * K + Koff + sg * 8;
    const ushort* Bg = Bt + (size_t)(bn + rr) * K + Koff + sg * 8;

    f32x4 acc[4][NT];
    #pragma unroll
    for (int i = 0; i < 4; ++i)
        #pragma unroll
        for (int j = 0; j < NT; ++j)
            acc[i][j] = (f32x4){0.f, 0.f, 0.f, 0.f};

    // prologue: stage k=0 into buffer 0
    gl2lds16(Ag,                  As + wave * 512);
    gl2lds16(Ag + (size_t)64 * K, As + 2048 + wave * 512);
    gl2lds16(Bg,                  Bs + wave * 512);
    if (TN == 128)
        gl2lds16(Bg + (size_t)64 * K, Bs + 2048 + wave * 512);

    int ib = 0;
    for (int k0 = 0; k0 < KS; k0 += 32, ib ^= 1) {
        __syncthreads();   // drains vmcnt: buffer ib is ready; buffer ib^1 free
        if (k0 + 32 < KS) {
            const int nb = ib ^ 1;
            gl2lds16(Ag + k0 + 32,                  As + nb * 4096 + wave * 512);
            gl2lds16(Ag + k0 + 32 + (size_t)64 * K, As + nb * 4096 + 2048 + wave * 512);
            gl2lds16(Bg + k0 + 32,                  Bs + nb * BSZ + wave * 512);
            if (TN == 128)
                gl2lds16(Bg + k0 + 32 + (size_t)64 * K, Bs + nb * BSZ + 2048 + wave * 512);
        }

        const ushort* Ar = As + ib * 4096;
        const ushort* Br = Bs + ib * BSZ;
        bf16x8 af[4], bf[NT];
        #pragma unroll
        for (int mt = 0; mt < 4; ++mt)
            af[mt] = *(const bf16x8*)(Ar + (wm + mt * 16 + lr) * 32 + lq * 8);
        #pragma unroll
        for (int nt = 0; nt < NT; ++nt)
            bf[nt] = *(const bf16x8*)(Br + (wn + nt * 16 + lr) * 32 + lq * 8);

        #pragma unroll
        for (int mt = 0; mt < 4; ++mt)
            #pragma unroll
            for (int nt = 0; nt < NT; ++nt)
                acc[mt][nt] = __builtin_amdgcn_mfma_f32_16x16x32_bf16(
                    af[mt], bf[nt], acc[mt][nt], 0, 0, 0);
    }

    // Epilogue. C/D layout: col = lane&15, row = (lane>>4)*4 + r
    if (SPLITK > 1) {
        ushort* Cp = Cb + (size_t)blockIdx.z * M * N;
        #pragma unroll
        for (int nt = 0; nt < NT; ++nt) {
            const int n = bn + wn + nt * 16 + lr;
            #pragma unroll
            for (int mt = 0; mt < 4; ++mt) {
                const int m0 = bm + wm + mt * 16 + lq * 4;
                #pragma unroll
                for (int r = 0; r < 4; ++r)
                    Cp[(size_t)(m0 + r) * N + n] = f2bf(acc[mt][nt][r]);
            }
        }
        return;
    }
    if (VOUT && bn >= 2 * Dm) {
        #pragma unroll
        for (int nt = 0; nt < NT; ++nt) {
            const int n = bn + wn + nt * 16 + lr;
            const float bv = bias[n];
            const int col = n - 2 * Dm;          // 0..1023
            const int h = col >> 6, d = col & 63;
            #pragma unroll
            for (int mt = 0; mt < 4; ++mt) {
                const int m0 = bm + wm + mt * 16 + lq * 4;
                const int batch = m0 >> 11, key0 = m0 & (Ls - 1);
                ushort4 ob;
                ushort* op = (ushort*)&ob;
                #pragma unroll
                for (int r = 0; r < 4; ++r) op[r] = f2bf(acc[mt][nt][r] + bv);
                *(ushort4*)(vT + (((size_t)(batch * Hh + h)) * HDd + d) * Ls + key0) = ob;
            }
        }
        return;
    }
    #pragma unroll
    for (int nt = 0; nt < NT; ++nt) {
        const int n = bn + wn + nt * 16 + lr;
        const float bv = bias[n];
        #pragma unroll
        for (int mt = 0; mt < 4; ++mt) {
            const int m0 = bm + wm + mt * 16 + lq * 4;
            #pragma unroll
            for (int r = 0; r < 4; ++r) {
                float v = acc[mt][nt][r] + bv;
                if (RELU) v = fmaxf(v, 0.0f);
                Cb[(size_t)(m0 + r) * N + n] = f2bf(v);
            }
        }
    }
}

// ---------------------------------------------------------------------------
// MFMA flash attention, S^T formulation, no-max softmax, KV-SPLIT 2.
// Each block: 128 q x 1024 keys (kv half). Grid 1024 -> 4 blocks/CU
// (was 512 -> 2/CU, grid-limited latency bound: Mfma 22 / VALU 50 / Occ 18).
// Numerator partials (f32, unnormalized) -> npart[kv]; denominators -> dpart.
// attn_combine sums halves and normalizes. No-max softmax => pure addition.
// ---------------------------------------------------------------------------
__global__ __launch_bounds__(256) void attn_mfma(
    const ushort* __restrict__ qkv, const ushort* __restrict__ vT,
    float* __restrict__ npart, float* __restrict__ dpart)
{
    const int tid = threadIdx.x, wave = tid >> 6, lane = tid & 63;
    const int lr = lane & 15, lq = lane >> 4;
    // grid (16,16,4): swizzle (nwg=1024) -> XCD c gets 128 contiguous tiles
    int bx, h, z;
    {
        const int lin = (blockIdx.z * 16 + blockIdx.y) * 16 + blockIdx.x;
        const int swz = (lin & 7) * 128 + (lin >> 3);
        bx = swz & 15; h = (swz >> 4) & 15; z = swz >> 8;
    }
    const int n = z >> 1, kv = z & 1;
    const int kt0 = kv * (Ls / 2);
    const int q0 = bx * 128 + wave * 32;
    const size_t RS = 3 * Dm;
    const ushort* base  = qkv + (size_t)n * Ls * RS;
    const ushort* vbase = vT + (size_t)(n * Hh + h) * HDd * Ls;

    __shared__ __align__(16) ushort Kb[64 * 72];      // [key][d]
    __shared__ __align__(16) ushort Vt[64 * 72];      // [d][key]
    __shared__ __align__(16) ushort Pq[4][32 * 72];   // per-wave [q][key]

    // Q fragments (B-layout: n=lr=q, k=lq*8+j=d), prescaled 0.125*log2(e)
    bf16x8 qf[2][2];                                   // [ks][qh]
    {
        const float c = 0.18033688011112042f;
        #pragma unroll
        for (int qh = 0; qh < 2; ++qh) {
            const ushort* qg = base + (size_t)(q0 + qh * 16 + lr) * RS + h * HDd + lq * 8;
            bf16x8 t0 = *(const bf16x8*)(qg);
            bf16x8 t1 = *(const bf16x8*)(qg + 32);
            #pragma unroll
            for (int j = 0; j < 8; ++j) {
                qf[0][qh][j] = (short)f2b(b2f((ushort)t0[j]) * c);
                qf[1][qh][j] = (short)f2b(b2f((ushort)t1[j]) * c);
            }
        }
    }

    // all-ones A fragment for the denominator MFMA (1.0bf16 = 0x3F80)
    bf16x8 onesf;
    #pragma unroll
    for (int j = 0; j < 8; ++j) onesf[j] = (short)0x3F80;
    const f32x4 z4 = (f32x4){0.f, 0.f, 0.f, 0.f};

    f32x4 o[4][2];                                     // [dt][qh]
    #pragma unroll
    for (int dt = 0; dt < 4; ++dt)
        #pragma unroll
        for (int qh = 0; qh < 2; ++qh)
            o[dt][qh] = (f32x4){0.f, 0.f, 0.f, 0.f};
    f32x4 dacc[2];                                     // denominator acc
    dacc[0] = (f32x4){0.f, 0.f, 0.f, 0.f};
    dacc[1] = (f32x4){0.f, 0.f, 0.f, 0.f};

    const int srow = tid >> 2, ssg = tid & 3;
    const ushort* kg = base + (size_t)srow * RS + Dm + h * HDd;
    const ushort* vg = vbase + (size_t)srow * Ls;
    ushort* Pw = Pq[wave];

    // prefetch first tile of this kv half into registers
    {
        const ushort* kp = kg + (size_t)kt0 * RS;
        const ushort* vp = vg + kt0;
        // (declared below via first loop iteration pattern)
    }
    int4 ka = *(const int4*)(kg + (size_t)kt0 * RS + ssg * 8);
    int4 kb = *(const int4*)(kg + (size_t)kt0 * RS + (ssg + 4) * 8);
    int4 va = *(const int4*)(vg + kt0 + ssg * 8);
    int4 vb = *(const int4*)(vg + kt0 + (ssg + 4) * 8);

    for (int kt = kt0; kt < kt0 + Ls / 2; kt += 64) {
        __syncthreads();            // all reads of previous tile done
        *(int4*)(Kb + srow * 72 + ssg * 8)       = ka;
        *(int4*)(Kb + srow * 72 + (ssg + 4) * 8) = kb;
        *(int4*)(Vt + srow * 72 + ssg * 8)       = va;
        *(int4*)(Vt + srow * 72 + (ssg + 4) * 8) = vb;
        __syncthreads();

        // T14: issue next tile's global loads; latency hides under compute
        if (kt + 64 < kt0 + Ls / 2) {
            const ushort* kp = kg + (size_t)(kt + 64) * RS;
            const ushort* vp = vg + (kt + 64);
            ka = *(const int4*)(kp + ssg * 8);
            kb = *(const int4*)(kp + (ssg + 4) * 8);
            va = *(const int4*)(vp + ssg * 8);
            vb = *(const int4*)(vp + (ssg + 4) * 8);
        }

        // S^T = K Q^T : [64 key][32 q], exp2 domain; K-frag shared by both qh
        f32x4 s[4][2];
        #pragma unroll
        for (int ks = 0; ks < 2; ++ks)
            #pragma unroll
            for (int mt = 0; mt < 4; ++mt) {
                bf16x8 kf = *(const bf16x8*)(Kb + (mt * 16 + lr) * 72 + ks * 32 + lq * 8);
                #pragma unroll
                for (int qh = 0; qh < 2; ++qh)
                    s[mt][qh] = __builtin_amdgcn_mfma_f32_16x16x32_bf16(
                        kf, qf[ks][qh], ks == 0 ? z4 : s[mt][qh], 0, 0, 0);
            }

        // p = exp2(s), pack bf16 pairs with v_cvt_pk_bf16_f32
        uint2 pb[4][2];
        #pragma unroll
        for (int mt = 0; mt < 4; ++mt)
            #pragma unroll
            for (int qh = 0; qh < 2; ++qh) {
                float p0 = EXP2(s[mt][qh][0]);
                float p1 = EXP2(s[mt][qh][1]);
                float p2 = EXP2(s[mt][qh][2]);
                float p3 = EXP2(s[mt][qh][3]);
                uint32_t w0, w1;
                asm("v_cvt_pk_bf16_f32 %0, %1, %2" : "=v"(w0) : "v"(p0), "v"(p1));
                asm("v_cvt_pk_bf16_f32 %0, %1, %2" : "=v"(w1) : "v"(p2), "v"(p3));
                pb[mt][qh].x = w0;
                pb[mt][qh].y = w1;
            }

        // P^T to per-wave LDS: [q][key], q = qh*16 + lr
        #pragma unroll
        for (int qh = 0; qh < 2; ++qh)
            #pragma unroll
            for (int mt = 0; mt < 4; ++mt)
                *(uint2*)(Pw + (qh * 16 + lr) * 72 + mt * 16 + lq * 4) = pb[mt][qh];

        // O^T += V^T P^T ; V-frag shared by both qh; denom += 1^T P^T
        #pragma unroll
        for (int ks = 0; ks < 2; ++ks) {
            bf16x8 pf[2];
            #pragma unroll
            for (int qh = 0; qh < 2; ++qh)
                pf[qh] = *(const bf16x8*)(Pw + (qh * 16 + lr) * 72 + ks * 32 + lq * 8);
            #pragma unroll
            for (int dt = 0; dt < 4; ++dt) {
                bf16x8 vf = *(const bf16x8*)(Vt + (dt * 16 + lr) * 72 + ks * 32 + lq * 8);
                #pragma unroll
                for (int qh = 0; qh < 2; ++qh)
                    o[dt][qh] = __builtin_amdgcn_mfma_f32_16x16x32_bf16(
                        vf, pf[qh], o[dt][qh], 0, 0, 0);
            }
            #pragma unroll
            for (int qh = 0; qh < 2; ++qh)
                dacc[qh] = __builtin_amdgcn_mfma_f32_16x16x32_bf16(
                    onesf, pf[qh], dacc[qh], 0, 0, 0);
        }
    }

    // write f32 numerator partials [kv][n][q][h*64+d] and denominators
    const int idx = kv * Nb + n;
    #pragma unroll
    for (int qh = 0; qh < 2; ++qh) {
        float* nrow = npart + ((size_t)idx * Ls + q0 + qh * 16 + lr) * Dm + h * HDd;
        #pragma unroll
        for (int dt = 0; dt < 4; ++dt) {
            float4 o4 = {o[dt][qh][0], o[dt][qh][1], o[dt][qh][2], o[dt][qh][3]};
            *(float4*)(nrow + dt * 16 + lq * 4) = o4;
        }
        if (lane < 16)
            dpart[((size_t)idx * Hh + h) * Ls + q0 + qh * 16 + lane] = dacc[qh][0];
    }
}

// ---------------------------------------------------------------------------
// attnb[row] = (n0 + n1) / (d0 + d1), bf16. row = n*Ls+q; 4 floats/thread.
// ---------------------------------------------------------------------------
__global__ __launch_bounds__(256) void attn_combine(
    const float* __restrict__ npart, const float* __restrict__ dpart,
    ushort* __restrict__ out)
{
    const int row = blockIdx.x;            // n*Ls + q
    const int tid = threadIdx.x;
    const int n = row >> 11, q = row & (Ls - 1);
    const int h = tid >> 4;                // 16 threads x 4 floats = 64 d per head

    const size_t b0 = ((size_t)(0 * Nb + n) * Ls + q) * Dm;
    const size_t b1 = ((size_t)(1 * Nb + n) * Ls + q) * Dm;
    float4 a = ((const float4*)(npart + b0))[tid];
    float4 b = ((const float4*)(npart + b1))[tid];
    const float d0 = dpart[((size_t)(0 * Nb + n) * Hh + h) * Ls + q];
    const float d1 = dpart[((size_t)(1 * Nb + n) * Hh + h) * Ls + q];
    const float inv = 1.0f / (d0 + d1);

    ushort4 ob;
    ob.x = f2bf((a.x + b.x) * inv);
    ob.y = f2bf((a.y + b.y) * inv);
    ob.z = f2bf((a.z + b.z) * inv);
    ob.w = f2bf((a.w + b.w) * inv);
    *(ushort4*)(out + (size_t)row * Dm + tid * 4) = ob;
}

// ---------------------------------------------------------------------------
// out = LayerNorm(p0 + p1 + bias + other) * gamma + beta.
// ---------------------------------------------------------------------------
template <int OTHER_BF16, int OUT_F32>
__global__ __launch_bounds__(256) void add3_ln(
    const ushort* __restrict__ part, const void* __restrict__ other,
    const float* __restrict__ bias,
    const float* __restrict__ gamma, const float* __restrict__ beta,
    float* __restrict__ outf, ushort* __restrict__ outb)
{
    const int row = blockIdx.x;
    const int tid = threadIdx.x;

    ushort4 u0 = ((const ushort4*)(part + (size_t)row * Dm))[tid];
    ushort4 u1 = ((const ushort4*)(part + (size_t)Mrows * Dm + (size_t)row * Dm))[tid];
    float4  bv = ((const float4*)bias)[tid];

    float vo[4];
    if (OTHER_BF16) {
        ushort4 u = ((const ushort4*)((const ushort*)other + (size_t)row * Dm))[tid];
        vo[0] = b2f(u.x); vo[1] = b2f(u.y); vo[2] = b2f(u.z); vo[3] = b2f(u.w);
    } else {
        float4 f = ((const float4*)((const float*)other + (size_t)row * Dm))[tid];
        vo[0] = f.x; vo[1] = f.y; vo[2] = f.z; vo[3] = f.w;
    }
    float v[4];
    v[0] = b2f(u0.x) + b2f(u1.x) + bv.x + vo[0];
    v[1] = b2f(u0.y) + b2f(u1.y) + bv.y + vo[1];
    v[2] = b2f(u0.z) + b2f(u1.z) + bv.z + vo[2];
    v[3] = b2f(u0.w) + b2f(u1.w) + bv.w + vo[3];

    float s  = v[0] + v[1] + v[2] + v[3];
    float sq = v[0]*v[0] + v[1]*v[1] + v[2]*v[2] + v[3]*v[3];

    __shared__ float red[8];
    #pragma unroll
    for (int off = 32; off > 0; off >>= 1) {
        s  += __shfl_down(s, off);
        sq += __shfl_down(sq, off);
    }
    const int wv = tid >> 6;
    if ((tid & 63) == 0) { red[wv] = s; red[4 + wv] = sq; }
    __syncthreads();
    s  = red[0] + red[1] + red[2] + red[3];
    sq = red[4] + red[5] + red[6] + red[7];

    const float mu  = s * (1.0f / Dm);
    const float var = sq * (1.0f / Dm) - mu * mu;
    const float inv = rsqrtf(var + 1e-5f);

    const float4 g  = ((const float4*)gamma)[tid];
    const float4 be = ((const float4*)beta)[tid];
    float ov[4];
    ov[0] = (v[0] - mu) * inv * g.x + be.x;
    ov[1] = (v[1] - mu) * inv * g.y + be.y;
    ov[2] = (v[2] - mu) * inv * g.z + be.z;
    ov[3] = (v[3] - mu) * inv * g.w + be.w;
    if (OUT_F32) {
        float4 o4 = {ov[0], ov[1], ov[2], ov[3]};
        ((float4*)(outf + (size_t)row * Dm))[tid] = o4;
    } else {
        uint2 ob;
        ob.x = (uint32_t)f2bf(ov[0]) | ((uint32_t)f2bf(ov[1]) << 16);
        ob.y = (uint32_t)f2bf(ov[2]) | ((uint32_t)f2bf(ov[3]) << 16);
        *(uint2*)(outb + (size_t)row * Dm + tid * 4) = ob;
    }
}

// ---------------------------------------------------------------------------
extern "C" void kernel_launch(void* const* d_in, const int* in_sizes, int n_in,
                              void* d_out, int out_size, void* d_ws, size_t ws_size,
                              hipStream_t stream)
{
    const float* x     = (const float*)d_in[0];
    const float* w_qkv = (const float*)d_in[1];
    const float* b_qkv = (const float*)d_in[2];
    const float* w_o   = (const float*)d_in[3];
    const float* b_o   = (const float*)d_in[4];
    const float* g1    = (const float*)d_in[5];
    const float* be1   = (const float*)d_in[6];
    const float* w1    = (const float*)d_in[7];
    const float* b1    = (const float*)d_in[8];
    const float* w2    = (const float*)d_in[9];
    const float* b2    = (const float*)d_in[10];
    const float* g2    = (const float*)d_in[11];
    const float* be2   = (const float*)d_in[12];
    float* out = (float*)d_out;

    char* p = (char*)d_ws;
    ushort* qkvb  = (ushort*)p;  p += (size_t)Mrows * 3 * Dm * 2;
    ushort* attnb = (ushort*)p;  p += (size_t)Mrows * Dm * 2;
    ushort* part  = (ushort*)p;  p += (size_t)2 * Mrows * Dm * 2;   // split-K partials
    ushort* hb    = (ushort*)p;  p += (size_t)Mrows * Dm * 2;
    ushort* ffb   = (ushort*)p;  p += (size_t)Mrows * FFd * 2;
    ushort* xb    = (ushort*)p;  p += (size_t)Mrows * Dm * 2;
    ushort* wqkvT = (ushort*)p;  p += (size_t)(3 * Dm) * Dm * 2;
    ushort* woT   = (ushort*)p;  p += (size_t)Dm * Dm * 2;
    ushort* w1T   = (ushort*)p;  p += (size_t)FFd * Dm * 2;
    ushort* w2T   = (ushort*)p;  p += (size_t)Dm * FFd * 2;
    ushort* vTg   = (ushort*)p;  p += (size_t)Mrows * Dm * 2;

    // attn KV-split scratch (aliases: ffb dead until ff GEMM; part dead until proj)
    float* npart = (float*)ffb;     // 2 * Mrows * Dm * 4B = 32 MB == ffb size
    float* dpart = (float*)part;    // 2 * Nb * Hh * Ls * 4B = 512 KB << part size

    convert_bf16<<<dim3(Mrows * Dm / 1024), dim3(256), 0, stream>>>(x, xb, Mrows * Dm);
    transpose_bf16<<<dim3(3 * Dm / 32, Dm / 32), dim3(256), 0, stream>>>(w_qkv, wqkvT, Dm, 3 * Dm);
    transpose_bf16<<<dim3(Dm / 32, Dm / 32),     dim3(256), 0, stream>>>(w_o, woT, Dm, Dm);
    transpose_bf16<<<dim3(FFd / 32, Dm / 32),    dim3(256), 0, stream>>>(w1, w1T, Dm, FFd);
    transpose_bf16<<<dim3(Dm / 32, FFd / 32),    dim3(256), 0, stream>>>(w2, w2T, FFd, Dm);

    // qkv = x @ w_qkv + b_qkv; Q,K -> qkvb rows, V -> vTg (transposed)
    gemm_mfma<128, 0, 1, 1><<<dim3(3 * Dm / 128, Mrows / 128), dim3(256), 0, stream>>>(
        xb, wqkvT, b_qkv, qkvb, vTg, Mrows, 3 * Dm, Dm);

    // attn: KV-split 2, f32 numerator/denominator partials
    attn_mfma<<<dim3(Ls / 128, Hh, 2 * Nb), dim3(256), 0, stream>>>(qkvb, vTg, npart, dpart);
    attn_combine<<<dim3(Mrows), dim3(256), 0, stream>>>(npart, dpart, attnb);

    // proj partials = attn @ w_o (split-K 2, bf16 partials, no bias)
    gemm_mfma<64, 0, 0, 2><<<dim3(Dm / 64, Mrows / 128, 2), dim3(256), 0, stream>>>(
        attnb, woT, nullptr, part, nullptr, Mrows, Dm, Dm);

    // h = LN(p0 + p1 + b_o + x) -> bf16
    add3_ln<0, 0><<<dim3(Mrows), dim3(256), 0, stream>>>(
        part, x, b_o, g1, be1, nullptr, hb);

    // ff = relu(h @ w1 + b1) (bf16)
    gemm_mfma<128, 1, 0, 1><<<dim3(FFd / 128, Mrows / 128), dim3(256), 0, stream>>>(
        hb, w1T, b1, ffb, nullptr, Mrows, FFd, Dm);

    // ff2 partials = ff @ w2 (split-K 2, bf16 partials, no bias)
    gemm_mfma<64, 0, 0, 2><<<dim3(Dm / 64, Mrows / 128, 2), dim3(256), 0, stream>>>(
        ffb, w2T, nullptr, part, nullptr, Mrows, Dm, FFd);

    // out = LN(p0 + p1 + b2 + h) -> fp32
    add3_ln<1, 1><<<dim3(Mrows), dim3(256), 0, stream>>>(
        part, hb, b2, g2, be2, out, nullptr);
}

// Round 6
// 379.324 us; speedup vs baseline: 1.0183x; 1.0183x over previous
//
#include <hip/hip_runtime.h>
#include <cstddef>
#include <cstdint>

static constexpr int Dm   = 1024;
static constexpr int Hh   = 16;
static constexpr int HDd  = 64;
static constexpr int FFd  = 4096;
static constexpr int Ls   = 2048;
static constexpr int Nb   = 2;
static constexpr int Mrows = Nb * Ls;   // 4096

typedef short bf16x8 __attribute__((ext_vector_type(8)));
typedef float f32x4  __attribute__((ext_vector_type(4)));

#if __has_builtin(__builtin_amdgcn_exp2f)
#define EXP2(x) __builtin_amdgcn_exp2f(x)
#else
#define EXP2(x) exp2f(x)
#endif

__device__ __forceinline__ ushort f2b(float f) {        // RNE (pre-pass)
    uint32_t u = __builtin_bit_cast(uint32_t, f);
    u = (u + 0x7FFFu + ((u >> 16) & 1u)) >> 16;
    return (ushort)u;
}
__device__ __forceinline__ ushort f2bf(float f) {       // fast round-half-up
    return (ushort)((__builtin_bit_cast(uint32_t, f) + 0x8000u) >> 16);
}
__device__ __forceinline__ float b2f(ushort b) {
    return __builtin_bit_cast(float, (uint32_t)b << 16);
}

__device__ __forceinline__ void gl2lds16(const ushort* g, ushort* l) {
    __builtin_amdgcn_global_load_lds(
        (const __attribute__((address_space(1))) void*)g,
        (__attribute__((address_space(3))) void*)l, 16, 0, 0);
}

// ---------------------------------------------------------------------------
__global__ __launch_bounds__(256) void convert_bf16(
    const float* __restrict__ src, ushort* __restrict__ dst, int n)
{
    int i = (blockIdx.x * 256 + threadIdx.x) * 4;
    if (i >= n) return;
    float4 v = *(const float4*)(src + i);
    uint2 o;
    o.x = (uint32_t)f2b(v.x) | ((uint32_t)f2b(v.y) << 16);
    o.y = (uint32_t)f2b(v.z) | ((uint32_t)f2b(v.w) << 16);
    *(uint2*)(dst + i) = o;
}

// ---------------------------------------------------------------------------
__global__ __launch_bounds__(256) void transpose_bf16(
    const float* __restrict__ src, ushort* __restrict__ dst, int K, int N)
{
    __shared__ float t[32][33];
    const int k0 = blockIdx.y * 32, n0 = blockIdx.x * 32;
    const int tx = threadIdx.x & 31, ty = threadIdx.x >> 5;
    #pragma unroll
    for (int i = 0; i < 4; ++i)
        t[ty + i * 8][tx] = src[(size_t)(k0 + ty + i * 8) * N + n0 + tx];
    __syncthreads();
    #pragma unroll
    for (int i = 0; i < 4; ++i)
        dst[(size_t)(n0 + ty + i * 8) * K + k0 + tx] = f2b(t[tx][ty + i * 8]);
}

// ---------------------------------------------------------------------------
// bf16 MFMA GEMM, double-buffered LDS, ONE barrier per K-iter.
// C[M,N] = A[M,K] @ Bt[N,K]^T + bias. 128 x TN tile (TN=128|64), 256 thr,
// BK=32, global_load_lds 16B into alternating buffers.
// SPLITK>1: grid.z = K-slice; bf16 partials to Cb + kz*M*N; add3_ln combines.
// T1: XCD-aware tile swizzle so each XCD's L2 keeps a contiguous A-panel run.
// ---------------------------------------------------------------------------
template <int TN, int RELU, int VOUT, int SPLITK>
__global__ __launch_bounds__(256) void gemm_mfma(
    const ushort* __restrict__ A, const ushort* __restrict__ Bt,
    const float* __restrict__ bias,
    ushort* __restrict__ Cb, ushort* __restrict__ vT, int M, int N, int K)
{
    constexpr int NT  = TN / 32;                 // B n-frags per wave
    constexpr int BSZ = TN * 32;                 // Bs shorts per buffer
    __shared__ __align__(16) ushort As[2 * 128 * 32];
    __shared__ __align__(16) ushort Bs[2 * BSZ];

    const int tid  = threadIdx.x;
    int bx, by;
    {
        const int gx = gridDim.x;
        const int nwg = gx * gridDim.y;
        const int lin = blockIdx.y * gx + blockIdx.x;
        const int swz = (lin & 7) * (nwg >> 3) + (lin >> 3);
        by = swz / gx; bx = swz - by * gx;
    }
    const int bm   = by * 128, bn = bx * TN;
    const int wave = tid >> 6, lane = tid & 63;
    const int wm = (wave & 1) * 64;
    const int wn = (wave >> 1) * (TN / 2);
    const int lr = lane & 15, lq = lane >> 4;

    const int KS   = K / SPLITK;                 // K per slice
    const int Koff = (SPLITK > 1) ? blockIdx.z * KS : 0;

    const int rr = wave * 16 + (lane >> 2);
    const int sg = lane & 3;
    const ushort* Ag = A  + (size_t)(bm + rr) * K + Koff + sg * 8;
    const ushort* Bg = Bt + (size_t)(bn + rr) * K + Koff + sg * 8;

    f32x4 acc[4][NT];
    #pragma unroll
    for (int i = 0; i < 4; ++i)
        #pragma unroll
        for (int j = 0; j < NT; ++j)
            acc[i][j] = (f32x4){0.f, 0.f, 0.f, 0.f};

    // prologue: stage k=0 into buffer 0
    gl2lds16(Ag,                  As + wave * 512);
    gl2lds16(Ag + (size_t)64 * K, As + 2048 + wave * 512);
    gl2lds16(Bg,                  Bs + wave * 512);
    if (TN == 128)
        gl2lds16(Bg + (size_t)64 * K, Bs + 2048 + wave * 512);

    int ib = 0;
    for (int k0 = 0; k0 < KS; k0 += 32, ib ^= 1) {
        __syncthreads();   // drains vmcnt: buffer ib is ready; buffer ib^1 free
        if (k0 + 32 < KS) {
            const int nb = ib ^ 1;
            gl2lds16(Ag + k0 + 32,                  As + nb * 4096 + wave * 512);
            gl2lds16(Ag + k0 + 32 + (size_t)64 * K, As + nb * 4096 + 2048 + wave * 512);
            gl2lds16(Bg + k0 + 32,                  Bs + nb * BSZ + wave * 512);
            if (TN == 128)
                gl2lds16(Bg + k0 + 32 + (size_t)64 * K, Bs + nb * BSZ + 2048 + wave * 512);
        }

        const ushort* Ar = As + ib * 4096;
        const ushort* Br = Bs + ib * BSZ;
        bf16x8 af[4], bf[NT];
        #pragma unroll
        for (int mt = 0; mt < 4; ++mt)
            af[mt] = *(const bf16x8*)(Ar + (wm + mt * 16 + lr) * 32 + lq * 8);
        #pragma unroll
        for (int nt = 0; nt < NT; ++nt)
            bf[nt] = *(const bf16x8*)(Br + (wn + nt * 16 + lr) * 32 + lq * 8);

        #pragma unroll
        for (int mt = 0; mt < 4; ++mt)
            #pragma unroll
            for (int nt = 0; nt < NT; ++nt)
                acc[mt][nt] = __builtin_amdgcn_mfma_f32_16x16x32_bf16(
                    af[mt], bf[nt], acc[mt][nt], 0, 0, 0);
    }

    // Epilogue. C/D layout: col = lane&15, row = (lane>>4)*4 + r
    if (SPLITK > 1) {
        ushort* Cp = Cb + (size_t)blockIdx.z * M * N;
        #pragma unroll
        for (int nt = 0; nt < NT; ++nt) {
            const int n = bn + wn + nt * 16 + lr;
            #pragma unroll
            for (int mt = 0; mt < 4; ++mt) {
                const int m0 = bm + wm + mt * 16 + lq * 4;
                #pragma unroll
                for (int r = 0; r < 4; ++r)
                    Cp[(size_t)(m0 + r) * N + n] = f2bf(acc[mt][nt][r]);
            }
        }
        return;
    }
    if (VOUT && bn >= 2 * Dm) {
        #pragma unroll
        for (int nt = 0; nt < NT; ++nt) {
            const int n = bn + wn + nt * 16 + lr;
            const float bv = bias[n];
            const int col = n - 2 * Dm;          // 0..1023
            const int h = col >> 6, d = col & 63;
            #pragma unroll
            for (int mt = 0; mt < 4; ++mt) {
                const int m0 = bm + wm + mt * 16 + lq * 4;
                const int batch = m0 >> 11, key0 = m0 & (Ls - 1);
                ushort4 ob;
                ushort* op = (ushort*)&ob;
                #pragma unroll
                for (int r = 0; r < 4; ++r) op[r] = f2bf(acc[mt][nt][r] + bv);
                *(ushort4*)(vT + (((size_t)(batch * Hh + h)) * HDd + d) * Ls + key0) = ob;
            }
        }
        return;
    }
    #pragma unroll
    for (int nt = 0; nt < NT; ++nt) {
        const int n = bn + wn + nt * 16 + lr;
        const float bv = bias[n];
        #pragma unroll
        for (int mt = 0; mt < 4; ++mt) {
            const int m0 = bm + wm + mt * 16 + lq * 4;
            #pragma unroll
            for (int r = 0; r < 4; ++r) {
                float v = acc[mt][nt][r] + bv;
                if (RELU) v = fmaxf(v, 0.0f);
                Cb[(size_t)(m0 + r) * N + n] = f2bf(v);
            }
        }
    }
}

// ---------------------------------------------------------------------------
// MFMA flash attention, S^T formulation, no-max softmax, KV-SPLIT 2.
// Round 6: P stays ENTIRELY in registers. The V tile's key axis is staged
// into LDS permuted by pi(slot ks*32+lq*8+j) = (2ks+(j>>2))*16 + lq*4 + (j&3),
// chosen so the PV B-fragment for lane (lr,lq) is exactly the concatenation
// {pb[2ks], pb[2ks+1]} of the lane's own cvt_pk outputs (QK^T C-layout gives
// lane keys mt*16+lq*4+r at q=lr). MFMA sums over k in any order, so a
// consistent permutation of V's key axis and P's slot axis is exact.
// Removes the P LDS round-trip (12 LDS ops/tile/wave) and halves LDS
// (36.9 -> 18.4 KB): residency was LDS-capped at ~2 blocks/CU (Occ 23%).
// ---------------------------------------------------------------------------
__global__ __launch_bounds__(256) void attn_mfma(
    const ushort* __restrict__ qkv, const ushort* __restrict__ vT,
    float* __restrict__ npart, float* __restrict__ dpart)
{
    const int tid = threadIdx.x, wave = tid >> 6, lane = tid & 63;
    const int lr = lane & 15, lq = lane >> 4;
    // grid (16,16,4): swizzle (nwg=1024) -> XCD c gets 128 contiguous tiles
    int bx, h, z;
    {
        const int lin = (blockIdx.z * 16 + blockIdx.y) * 16 + blockIdx.x;
        const int swz = (lin & 7) * 128 + (lin >> 3);
        bx = swz & 15; h = (swz >> 4) & 15; z = swz >> 8;
    }
    const int n = z >> 1, kv = z & 1;
    const int kt0 = kv * (Ls / 2);
    const int q0 = bx * 128 + wave * 32;
    const size_t RS = 3 * Dm;
    const ushort* base  = qkv + (size_t)n * Ls * RS;
    const ushort* vbase = vT + (size_t)(n * Hh + h) * HDd * Ls;

    __shared__ __align__(16) ushort Kb[64 * 72];      // [key][d]
    __shared__ __align__(16) ushort Vt[64 * 72];      // [d][slot] (pi-permuted keys)

    // Q fragments (B-layout: n=lr=q, k=lq*8+j=d), prescaled 0.125*log2(e)
    bf16x8 qf[2][2];                                   // [ks][qh]
    {
        const float c = 0.18033688011112042f;
        #pragma unroll
        for (int qh = 0; qh < 2; ++qh) {
            const ushort* qg = base + (size_t)(q0 + qh * 16 + lr) * RS + h * HDd + lq * 8;
            bf16x8 t0 = *(const bf16x8*)(qg);
            bf16x8 t1 = *(const bf16x8*)(qg + 32);
            #pragma unroll
            for (int j = 0; j < 8; ++j) {
                qf[0][qh][j] = (short)f2b(b2f((ushort)t0[j]) * c);
                qf[1][qh][j] = (short)f2b(b2f((ushort)t1[j]) * c);
            }
        }
    }

    // all-ones A fragment for the denominator MFMA (1.0bf16 = 0x3F80)
    bf16x8 onesf;
    #pragma unroll
    for (int j = 0; j < 8; ++j) onesf[j] = (short)0x3F80;
    const f32x4 z4 = (f32x4){0.f, 0.f, 0.f, 0.f};

    f32x4 o[4][2];                                     // [dt][qh]
    #pragma unroll
    for (int dt = 0; dt < 4; ++dt)
        #pragma unroll
        for (int qh = 0; qh < 2; ++qh)
            o[dt][qh] = (f32x4){0.f, 0.f, 0.f, 0.f};
    f32x4 dacc[2];                                     // denominator acc
    dacc[0] = (f32x4){0.f, 0.f, 0.f, 0.f};
    dacc[1] = (f32x4){0.f, 0.f, 0.f, 0.f};

    const int srow = tid >> 2, ssg = tid & 3;
    const ushort* kg = base + (size_t)srow * RS + Dm + h * HDd;
    const ushort* vg = vbase + (size_t)srow * Ls;

    // V slot-permutation write bases: the 8 contiguous keys of each int4 load
    // split into two 4-key groups landing at slots sA/sB (see pi above).
    const int sA = (((2 * ssg) & 3) * 8) + (((ssg >> 1) & 1) * 4);
    const int sB = (((2 * ssg + 1) & 3) * 8) + (((ssg >> 1) & 1) * 4);

    // prefetch first tile of this kv half into registers
    int4 ka = *(const int4*)(kg + (size_t)kt0 * RS + ssg * 8);
    int4 kb = *(const int4*)(kg + (size_t)kt0 * RS + (ssg + 4) * 8);
    int4 va = *(const int4*)(vg + kt0 + ssg * 8);
    int4 vb = *(const int4*)(vg + kt0 + (ssg + 4) * 8);

    for (int kt = kt0; kt < kt0 + Ls / 2; kt += 64) {
        __syncthreads();            // all reads of previous tile done
        *(int4*)(Kb + srow * 72 + ssg * 8)       = ka;
        *(int4*)(Kb + srow * 72 + (ssg + 4) * 8) = kb;
        {
            ushort* vrow = Vt + srow * 72;
            *(uint2*)(vrow + sA)      = (uint2){(uint32_t)va.x, (uint32_t)va.y};
            *(uint2*)(vrow + sB)      = (uint2){(uint32_t)va.z, (uint32_t)va.w};
            *(uint2*)(vrow + 32 + sA) = (uint2){(uint32_t)vb.x, (uint32_t)vb.y};
            *(uint2*)(vrow + 32 + sB) = (uint2){(uint32_t)vb.z, (uint32_t)vb.w};
        }
        __syncthreads();

        // T14: issue next tile's global loads; latency hides under compute
        if (kt + 64 < kt0 + Ls / 2) {
            const ushort* kp = kg + (size_t)(kt + 64) * RS;
            const ushort* vp = vg + (kt + 64);
            ka = *(const int4*)(kp + ssg * 8);
            kb = *(const int4*)(kp + (ssg + 4) * 8);
            va = *(const int4*)(vp + ssg * 8);
            vb = *(const int4*)(vp + (ssg + 4) * 8);
        }

        // S^T = K Q^T : [64 key][32 q], exp2 domain; K-frag shared by both qh
        f32x4 s[4][2];
        #pragma unroll
        for (int ks = 0; ks < 2; ++ks)
            #pragma unroll
            for (int mt = 0; mt < 4; ++mt) {
                bf16x8 kf = *(const bf16x8*)(Kb + (mt * 16 + lr) * 72 + ks * 32 + lq * 8);
                #pragma unroll
                for (int qh = 0; qh < 2; ++qh)
                    s[mt][qh] = __builtin_amdgcn_mfma_f32_16x16x32_bf16(
                        kf, qf[ks][qh], ks == 0 ? z4 : s[mt][qh], 0, 0, 0);
            }

        // p = exp2(s), pack bf16 pairs with v_cvt_pk_bf16_f32.
        // pb[mt][qh] = keys {mt*16+lq*4+r}, q = lr.
        uint2 pb[4][2];
        #pragma unroll
        for (int mt = 0; mt < 4; ++mt)
            #pragma unroll
            for (int qh = 0; qh < 2; ++qh) {
                float p0 = EXP2(s[mt][qh][0]);
                float p1 = EXP2(s[mt][qh][1]);
                float p2 = EXP2(s[mt][qh][2]);
                float p3 = EXP2(s[mt][qh][3]);
                uint32_t w0, w1;
                asm("v_cvt_pk_bf16_f32 %0, %1, %2" : "=v"(w0) : "v"(p0), "v"(p1));
                asm("v_cvt_pk_bf16_f32 %0, %1, %2" : "=v"(w1) : "v"(p2), "v"(p3));
                pb[mt][qh].x = w0;
                pb[mt][qh].y = w1;
            }

        // O^T += V^T P^T over permuted slots; P fragment = register concat.
        #pragma unroll
        for (int ks = 0; ks < 2; ++ks) {
            bf16x8 pf[2];
            #pragma unroll
            for (int qh = 0; qh < 2; ++qh) {
                uint4 u = (uint4){pb[2 * ks][qh].x, pb[2 * ks][qh].y,
                                  pb[2 * ks + 1][qh].x, pb[2 * ks + 1][qh].y};
                pf[qh] = __builtin_bit_cast(bf16x8, u);
            }
            #pragma unroll
            for (int dt = 0; dt < 4; ++dt) {
                bf16x8 vf = *(const bf16x8*)(Vt + (dt * 16 + lr) * 72 + ks * 32 + lq * 8);
                #pragma unroll
                for (int qh = 0; qh < 2; ++qh)
                    o[dt][qh] = __builtin_amdgcn_mfma_f32_16x16x32_bf16(
                        vf, pf[qh], o[dt][qh], 0, 0, 0);
            }
            #pragma unroll
            for (int qh = 0; qh < 2; ++qh)
                dacc[qh] = __builtin_amdgcn_mfma_f32_16x16x32_bf16(
                    onesf, pf[qh], dacc[qh], 0, 0, 0);
        }
    }

    // write f32 numerator partials [kv][n][q][h*64+d] and denominators
    const int idx = kv * Nb + n;
    #pragma unroll
    for (int qh = 0; qh < 2; ++qh) {
        float* nrow = npart + ((size_t)idx * Ls + q0 + qh * 16 + lr) * Dm + h * HDd;
        #pragma unroll
        for (int dt = 0; dt < 4; ++dt) {
            float4 o4 = {o[dt][qh][0], o[dt][qh][1], o[dt][qh][2], o[dt][qh][3]};
            *(float4*)(nrow + dt * 16 + lq * 4) = o4;
        }
        if (lane < 16)
            dpart[((size_t)idx * Hh + h) * Ls + q0 + qh * 16 + lane] = dacc[qh][0];
    }
}

// ---------------------------------------------------------------------------
// attnb[row] = (n0 + n1) / (d0 + d1), bf16. row = n*Ls+q; 4 floats/thread.
// ---------------------------------------------------------------------------
__global__ __launch_bounds__(256) void attn_combine(
    const float* __restrict__ npart, const float* __restrict__ dpart,
    ushort* __restrict__ out)
{
    const int row = blockIdx.x;            // n*Ls + q
    const int tid = threadIdx.x;
    const int n = row >> 11, q = row & (Ls - 1);
    const int h = tid >> 4;                // 16 threads x 4 floats = 64 d per head

    const size_t b0 = ((size_t)(0 * Nb + n) * Ls + q) * Dm;
    const size_t b1 = ((size_t)(1 * Nb + n) * Ls + q) * Dm;
    float4 a = ((const float4*)(npart + b0))[tid];
    float4 b = ((const float4*)(npart + b1))[tid];
    const float d0 = dpart[((size_t)(0 * Nb + n) * Hh + h) * Ls + q];
    const float d1 = dpart[((size_t)(1 * Nb + n) * Hh + h) * Ls + q];
    const float inv = 1.0f / (d0 + d1);

    ushort4 ob;
    ob.x = f2bf((a.x + b.x) * inv);
    ob.y = f2bf((a.y + b.y) * inv);
    ob.z = f2bf((a.z + b.z) * inv);
    ob.w = f2bf((a.w + b.w) * inv);
    *(ushort4*)(out + (size_t)row * Dm + tid * 4) = ob;
}

// ---------------------------------------------------------------------------
// out = LayerNorm(p0 + p1 + bias + other) * gamma + beta.
// ---------------------------------------------------------------------------
template <int OTHER_BF16, int OUT_F32>
__global__ __launch_bounds__(256) void add3_ln(
    const ushort* __restrict__ part, const void* __restrict__ other,
    const float* __restrict__ bias,
    const float* __restrict__ gamma, const float* __restrict__ beta,
    float* __restrict__ outf, ushort* __restrict__ outb)
{
    const int row = blockIdx.x;
    const int tid = threadIdx.x;

    ushort4 u0 = ((const ushort4*)(part + (size_t)row * Dm))[tid];
    ushort4 u1 = ((const ushort4*)(part + (size_t)Mrows * Dm + (size_t)row * Dm))[tid];
    float4  bv = ((const float4*)bias)[tid];

    float vo[4];
    if (OTHER_BF16) {
        ushort4 u = ((const ushort4*)((const ushort*)other + (size_t)row * Dm))[tid];
        vo[0] = b2f(u.x); vo[1] = b2f(u.y); vo[2] = b2f(u.z); vo[3] = b2f(u.w);
    } else {
        float4 f = ((const float4*)((const float*)other + (size_t)row * Dm))[tid];
        vo[0] = f.x; vo[1] = f.y; vo[2] = f.z; vo[3] = f.w;
    }
    float v[4];
    v[0] = b2f(u0.x) + b2f(u1.x) + bv.x + vo[0];
    v[1] = b2f(u0.y) + b2f(u1.y) + bv.y + vo[1];
    v[2] = b2f(u0.z) + b2f(u1.z) + bv.z + vo[2];
    v[3] = b2f(u0.w) + b2f(u1.w) + bv.w + vo[3];

    float s  = v[0] + v[1] + v[2] + v[3];
    float sq = v[0]*v[0] + v[1]*v[1] + v[2]*v[2] + v[3]*v[3];

    __shared__ float red[8];
    #pragma unroll
    for (int off = 32; off > 0; off >>= 1) {
        s  += __shfl_down(s, off);
        sq += __shfl_down(sq, off);
    }
    const int wv = tid >> 6;
    if ((tid & 63) == 0) { red[wv] = s; red[4 + wv] = sq; }
    __syncthreads();
    s  = red[0] + red[1] + red[2] + red[3];
    sq = red[4] + red[5] + red[6] + red[7];

    const float mu  = s * (1.0f / Dm);
    const float var = sq * (1.0f / Dm) - mu * mu;
    const float inv = rsqrtf(var + 1e-5f);

    const float4 g  = ((const float4*)gamma)[tid];
    const float4 be = ((const float4*)beta)[tid];
    float ov[4];
    ov[0] = (v[0] - mu) * inv * g.x + be.x;
    ov[1] = (v[1] - mu) * inv * g.y + be.y;
    ov[2] = (v[2] - mu) * inv * g.z + be.z;
    ov[3] = (v[3] - mu) * inv * g.w + be.w;
    if (OUT_F32) {
        float4 o4 = {ov[0], ov[1], ov[2], ov[3]};
        ((float4*)(outf + (size_t)row * Dm))[tid] = o4;
    } else {
        uint2 ob;
        ob.x = (uint32_t)f2bf(ov[0]) | ((uint32_t)f2bf(ov[1]) << 16);
        ob.y = (uint32_t)f2bf(ov[2]) | ((uint32_t)f2bf(ov[3]) << 16);
        *(uint2*)(outb + (size_t)row * Dm + tid * 4) = ob;
    }
}

// ---------------------------------------------------------------------------
extern "C" void kernel_launch(void* const* d_in, const int* in_sizes, int n_in,
                              void* d_out, int out_size, void* d_ws, size_t ws_size,
                              hipStream_t stream)
{
    const float* x     = (const float*)d_in[0];
    const float* w_qkv = (const float*)d_in[1];
    const float* b_qkv = (const float*)d_in[2];
    const float* w_o   = (const float*)d_in[3];
    const float* b_o   = (const float*)d_in[4];
    const float* g1    = (const float*)d_in[5];
    const float* be1   = (const float*)d_in[6];
    const float* w1    = (const float*)d_in[7];
    const float* b1    = (const float*)d_in[8];
    const float* w2    = (const float*)d_in[9];
    const float* b2    = (const float*)d_in[10];
    const float* g2    = (const float*)d_in[11];
    const float* be2   = (const float*)d_in[12];
    float* out = (float*)d_out;

    char* p = (char*)d_ws;
    ushort* qkvb  = (ushort*)p;  p += (size_t)Mrows * 3 * Dm * 2;
    ushort* attnb = (ushort*)p;  p += (size_t)Mrows * Dm * 2;
    ushort* part  = (ushort*)p;  p += (size_t)2 * Mrows * Dm * 2;   // split-K partials
    ushort* hb    = (ushort*)p;  p += (size_t)Mrows * Dm * 2;
    ushort* ffb   = (ushort*)p;  p += (size_t)Mrows * FFd * 2;
    ushort* xb    = (ushort*)p;  p += (size_t)Mrows * Dm * 2;
    ushort* wqkvT = (ushort*)p;  p += (size_t)(3 * Dm) * Dm * 2;
    ushort* woT   = (ushort*)p;  p += (size_t)Dm * Dm * 2;
    ushort* w1T   = (ushort*)p;  p += (size_t)FFd * Dm * 2;
    ushort* w2T   = (ushort*)p;  p += (size_t)Dm * FFd * 2;
    ushort* vTg   = (ushort*)p;  p += (size_t)Mrows * Dm * 2;

    // attn KV-split scratch (aliases: ffb dead until ff GEMM; part dead until proj)
    float* npart = (float*)ffb;     // 2 * Mrows * Dm * 4B = 32 MB == ffb size
    float* dpart = (float*)part;    // 2 * Nb * Hh * Ls * 4B = 512 KB << part size

    convert_bf16<<<dim3(Mrows * Dm / 1024), dim3(256), 0, stream>>>(x, xb, Mrows * Dm);
    transpose_bf16<<<dim3(3 * Dm / 32, Dm / 32), dim3(256), 0, stream>>>(w_qkv, wqkvT, Dm, 3 * Dm);
    transpose_bf16<<<dim3(Dm / 32, Dm / 32),     dim3(256), 0, stream>>>(w_o, woT, Dm, Dm);
    transpose_bf16<<<dim3(FFd / 32, Dm / 32),    dim3(256), 0, stream>>>(w1, w1T, Dm, FFd);
    transpose_bf16<<<dim3(Dm / 32, FFd / 32),    dim3(256), 0, stream>>>(w2, w2T, FFd, Dm);

    // qkv = x @ w_qkv + b_qkv; Q,K -> qkvb rows, V -> vTg (transposed)
    gemm_mfma<128, 0, 1, 1><<<dim3(3 * Dm / 128, Mrows / 128), dim3(256), 0, stream>>>(
        xb, wqkvT, b_qkv, qkvb, vTg, Mrows, 3 * Dm, Dm);

    // attn: KV-split 2, f32 numerator/denominator partials
    attn_mfma<<<dim3(Ls / 128, Hh, 2 * Nb), dim3(256), 0, stream>>>(qkvb, vTg, npart, dpart);
    attn_combine<<<dim3(Mrows), dim3(256), 0, stream>>>(npart, dpart, attnb);

    // proj partials = attn @ w_o (split-K 2, bf16 partials, no bias)
    gemm_mfma<64, 0, 0, 2><<<dim3(Dm / 64, Mrows / 128, 2), dim3(256), 0, stream>>>(
        attnb, woT, nullptr, part, nullptr, Mrows, Dm, Dm);

    // h = LN(p0 + p1 + b_o + x) -> bf16
    add3_ln<0, 0><<<dim3(Mrows), dim3(256), 0, stream>>>(
        part, x, b_o, g1, be1, nullptr, hb);

    // ff = relu(h @ w1 + b1) (bf16)
    gemm_mfma<128, 1, 0, 1><<<dim3(FFd / 128, Mrows / 128), dim3(256), 0, stream>>>(
        hb, w1T, b1, ffb, nullptr, Mrows, FFd, Dm);

    // ff2 partials = ff @ w2 (split-K 2, bf16 partials, no bias)
    gemm_mfma<64, 0, 0, 2><<<dim3(Dm / 64, Mrows / 128, 2), dim3(256), 0, stream>>>(
        ffb, w2T, nullptr, part, nullptr, Mrows, Dm, FFd);

    // out = LN(p0 + p1 + b2 + h) -> fp32
    add3_ln<1, 1><<<dim3(Mrows), dim3(256), 0, stream>>>(
        part, hb, b2, g2, be2, out, nullptr);
}